// Round 6
// baseline (335.537 us; speedup 1.0000x reference)
//
#include <hip/hip_runtime.h>

// ---------------- problem constants ----------------
// B=4096 batch, D=2048 dim, H=3 hidden layers, O=1 output
#define BB 4096
#define DD 2048

typedef float f32x4 __attribute__((ext_vector_type(4)));
typedef __bf16 bf16x8 __attribute__((ext_vector_type(8)));

typedef __attribute__((address_space(1))) unsigned int gl_u32;
typedef __attribute__((address_space(3))) unsigned int lds_u32;

#define GLOAD_LDS16(gptr, sptr) \
  __builtin_amdgcn_global_load_lds((gl_u32*)(void*)(gptr), (lds_u32*)(sptr), 16, 0, 0)

// raw barrier with compiler memory fence (does NOT force vmcnt(0) drain like
// __syncthreads) — required for counted-vmcnt pipelining (T3/T4).
#define SBAR_MEM() asm volatile("s_barrier" ::: "memory")
#define VMCNT(n)   asm volatile("s_waitcnt vmcnt(" #n ")" ::: "memory")
#define LGKMCNT0() asm volatile("s_waitcnt lgkmcnt(0)" ::: "memory")

__device__ __forceinline__ unsigned short f2bf(float f) {
  unsigned int u = __float_as_uint(f);
  u += 0x7fffu + ((u >> 16) & 1u);   // round-to-nearest-even
  return (unsigned short)(u >> 16);
}

// fast softplus: v_exp_f32 + v_log_f32 (quarter-rate HW ops).
__device__ __forceinline__ float sp(float x) {
  float t = __expf(-fabsf(x));
  return fmaxf(x, 0.0f) + __logf(1.0f + t);
}

__device__ __forceinline__ void prep_w_vec4(
    const float* __restrict__ mu, const float* __restrict__ rho,
    const float* __restrict__ eps, unsigned short* __restrict__ Wh,
    long long i)
{
  float4 m = ((const float4*)mu)[i];
  float4 r = ((const float4*)rho)[i];
  float4 e = ((const float4*)eps)[i];
  ushort4 o;
  o.x = f2bf(m.x + e.x * sp(r.x));
  o.y = f2bf(m.y + e.y * sp(r.y));
  o.z = f2bf(m.z + e.z * sp(r.z));
  o.w = f2bf(m.w + e.w * sp(r.w));
  ((ushort4*)Wh)[i] = o;
}

__device__ __forceinline__ void prep_f32_vec4(
    const float* __restrict__ mu, const float* __restrict__ rho,
    const float* __restrict__ eps, float* __restrict__ out, long long i)
{
  float4 m = ((const float4*)mu)[i];
  float4 r = ((const float4*)rho)[i];
  float4 e = ((const float4*)eps)[i];
  float4 o;
  o.x = m.x + e.x * sp(r.x);
  o.y = m.y + e.y * sp(r.y);
  o.z = m.z + e.z * sp(r.z);
  o.w = m.w + e.w * sp(r.w);
  ((float4*)out)[i] = o;
}

// ---------------- prep0: ALL prep (R11) ----------------
// R5 post-mortem: fusing W1/W2 prep into the 144KiB-LDS GEMM kernel forced
// the memory-bound prep to 1 block/CU, fully serialized (+21us). Now prep0
// does everything: W0..W2 (blocks 0..1535), x (1536..2559), smalls (2560).
__global__ __launch_bounds__(512) void prep0_kernel(
    const float* __restrict__ x,
    const float* __restrict__ wmuh, const float* __restrict__ wrhoh,
    const float* __restrict__ bmuh, const float* __restrict__ brhoh,
    const float* __restrict__ wmuo, const float* __restrict__ wrhoo,
    const float* __restrict__ epswh, const float* __restrict__ epsbh,
    const float* __restrict__ epswo,
    unsigned short* __restrict__ Wh, unsigned short* __restrict__ Xb,
    float* __restrict__ bh, float* __restrict__ wo)
{
  const int b = blockIdx.x;
  const int t = threadIdx.x;
  if (b < 1536) {          // all 3 W layers: 3*2048*2048/4 = 3145728 vec4
    long long base = (long long)b * 2048 + t;
    #pragma unroll
    for (int j = 0; j < 4; ++j)
      prep_w_vec4(wmuh, wrhoh, epswh, Wh, base + j * 512);
    return;
  }
  if (b < 2560) {          // x -> bf16: 4096*2048/4 = 2097152 vec4
    long long base = (long long)(b - 1536) * 2048 + t;
    #pragma unroll
    for (int j = 0; j < 4; ++j) {
      float4 v = ((const float4*)x)[base + j * 512];
      ushort4 o;
      o.x = f2bf(v.x); o.y = f2bf(v.y); o.z = f2bf(v.z); o.w = f2bf(v.w);
      ((ushort4*)Xb)[base + j * 512] = o;
    }
    return;
  }
  // b == 2560: b0,b1,b2 (1536 vec4) + wo (512 vec4)
  #pragma unroll
  for (int j = 0; j < 3; ++j)
    prep_f32_vec4(bmuh, brhoh, epsbh, bh, j * 512 + t);
  prep_f32_vec4(wmuo, wrhoo, epswo, wo, t);
}

// ---------------- R11 GEMM core: 256x128, ring-3, PER-PHASE interleave ----
// R5's ring-3 + counted vmcnt was correct but null (guide regime-gate:
// counted vmcnt on a coarse 2-phase loop ≈ drain-0; the lever is the
// per-phase ds_read ∥ stage ∥ MFMA interleave). Each K-tile = 2 phases:
//   phase: {stage-issue(3 gload_lds) ∥ ds_read(8 b128) -> lgkmcnt(0)
//           + sched_barrier -> setprio(1) 16 MFMA setprio(0) -> s_barrier}
// 16 MFMA/phase = m201's phase density. vmcnt(9) once per tile (never 0
// until tail). 8 waves as 4Mx2N, wave tile 64x64, acc[4][4].
// vmcnt ledger (6 loads/tile, 3 per phase): entering tile k outstanding =
// stage(k)[6]+stage(k+1)[6]=12; phase0 issues 3 of stage(k+2) -> 15;
// vmcnt(9) retires stage(k) exactly. Tail: k==30 -> vmcnt(6), k==31 -> 0.
// Ring-3 reuse: stage(k+2) targets buf[(k+2)%3], last read at tile k-1,
// whose trailing barrier precedes this issue. XOR swizzle (T2) unchanged.
#define NGEMM 256

struct Coords256 { int m0, n0; int srow[4], sgc[4]; };

__device__ __forceinline__ Coords256 coords256(int id, int t) {
  Coords256 g;
  const int p = id & 7;        // XCD patch (L2 locality)
  const int i4 = id >> 3;      // 0..31 within patch
  const int mt = (p & 3) * 4 + (i4 & 3);     // 0..15
  const int nt = (p >> 2) * 8 + (i4 >> 2);   // 0..15
  g.m0 = mt * 256;
  g.n0 = nt * 128;
  #pragma unroll
  for (int i = 0; i < 4; ++i) {
    int c = i * 512 + t;
    g.srow[i] = c >> 3;                      // 0..255
    g.sgc[i] = (c & 7) ^ (g.srow[i] & 7);    // XOR swizzle folded into gsrc
  }
  return g;
}

// half 0: A rows 0..127 (2 loads) + B rows 0..63 (1 load)
__device__ __forceinline__ void stage_half0(
    const unsigned short* __restrict__ A, const unsigned short* __restrict__ W,
    unsigned short* bufA, unsigned short* bufB,
    const Coords256& gc, int kt, int t)
{
  #pragma unroll
  for (int i = 0; i < 2; ++i) {
    int c = i * 512 + t;
    const unsigned short* ga = A + (size_t)(gc.m0 + gc.srow[i]) * DD + kt + gc.sgc[i] * 8;
    GLOAD_LDS16(ga, &bufA[c * 8]);
  }
  const unsigned short* gb = W + (size_t)(gc.n0 + gc.srow[0]) * DD + kt + gc.sgc[0] * 8;
  GLOAD_LDS16(gb, &bufB[t * 8]);
}

// half 1: A rows 128..255 (2 loads) + B rows 64..127 (1 load)
__device__ __forceinline__ void stage_half1(
    const unsigned short* __restrict__ A, const unsigned short* __restrict__ W,
    unsigned short* bufA, unsigned short* bufB,
    const Coords256& gc, int kt, int t)
{
  #pragma unroll
  for (int i = 2; i < 4; ++i) {
    int c = i * 512 + t;
    const unsigned short* ga = A + (size_t)(gc.m0 + gc.srow[i]) * DD + kt + gc.sgc[i] * 8;
    GLOAD_LDS16(ga, &bufA[c * 8]);
  }
  const unsigned short* gb = W + (size_t)(gc.n0 + gc.srow[1]) * DD + kt + gc.sgc[1] * 8;
  GLOAD_LDS16(gb, &bufB[(512 + t) * 8]);
}

// one phase: ds_read 8 x b128 for k-half s, then 16 MFMA under setprio.
__device__ __forceinline__ void compute_half(
    const unsigned short* bufA, const unsigned short* bufB, int s,
    int wm, int wn, int lq, int lr, f32x4 (&acc)[4][4])
{
  bf16x8 af[4], bfv[4];
  const int g = s * 4 + lq;
  const int go = (g ^ (lr & 7)) * 8;   // row&7 == lr&7 (wm*64, i*16 mult of 8)
  #pragma unroll
  for (int i = 0; i < 4; ++i) {
    int ra = wm * 64 + i * 16 + lr;
    af[i] = *(const bf16x8*)&bufA[ra * 64 + go];
  }
  #pragma unroll
  for (int j = 0; j < 4; ++j) {
    int rb = wn * 64 + j * 16 + lr;
    bfv[j] = *(const bf16x8*)&bufB[rb * 64 + go];
  }
  LGKMCNT0();
  __builtin_amdgcn_sched_barrier(0);   // rule 18: keep MFMA below the wait
  __builtin_amdgcn_s_setprio(1);
  #pragma unroll
  for (int i = 0; i < 4; ++i)
    #pragma unroll
    for (int j = 0; j < 4; ++j)
      acc[i][j] = __builtin_amdgcn_mfma_f32_16x16x32_bf16(af[i], bfv[j], acc[i][j], 0, 0, 0);
  __builtin_amdgcn_s_setprio(0);
}

__device__ __forceinline__ void gemm_mainloop8p(
    const unsigned short* __restrict__ A, const unsigned short* __restrict__ W,
    unsigned short (*ldsA)[16384], unsigned short (*ldsB)[8192],
    const Coords256& gc, int t, f32x4 (&acc)[4][4])
{
  const int l = t & 63, lq = l >> 4, lr = l & 15;
  const int w = t >> 6, wm = w & 3, wn = w >> 2;
  unsigned short *a0 = ldsA[0], *a1 = ldsA[1], *a2 = ldsA[2];
  unsigned short *b0 = ldsB[0], *b1 = ldsB[1], *b2 = ldsB[2];
  // prologue: tiles 0,1 fully staged (12 loads outstanding)
  stage_half0(A, W, a0, b0, gc, 0, t);
  stage_half1(A, W, a0, b0, gc, 0, t);
  stage_half0(A, W, a1, b1, gc, 64, t);
  stage_half1(A, W, a1, b1, gc, 64, t);
  for (int k = 0; k < 32; ++k) {
    // ---- phase 0 ----
    if (k < 30) stage_half0(A, W, a2, b2, gc, (k + 2) * 64, t);
    __builtin_amdgcn_sched_barrier(0);   // pin stage-issue before the count
    if (k < 30)      { VMCNT(9); }       // retire exactly stage(k)
    else if (k == 30){ VMCNT(6); }
    else             { VMCNT(0); }
    SBAR_MEM();                          // buf k certified for all waves
    compute_half(a0, b0, 0, wm, wn, lq, lr, acc);
    SBAR_MEM();
    // ---- phase 1 ----
    if (k < 30) stage_half1(A, W, a2, b2, gc, (k + 2) * 64, t);
    compute_half(a0, b0, 1, wm, wn, lq, lr, acc);
    SBAR_MEM();                          // all waves done reading buf k
    unsigned short* ta = a0; a0 = a1; a1 = a2; a2 = ta;
    unsigned short* tb = b0; b0 = b1; b1 = b2; b2 = tb;
  }
}

__device__ __forceinline__ void epilogue_store256(
    const Coords256& gc, int t, f32x4 (&acc)[4][4],
    const float* __restrict__ bias, unsigned short* __restrict__ C)
{
  const int l = t & 63, lq = l >> 4, lr = l & 15;
  const int w = t >> 6, wm = w & 3, wn = w >> 2;
  #pragma unroll
  for (int j = 0; j < 4; ++j) {
    int n = gc.n0 + wn * 64 + j * 16 + lr;
    float bv = bias[n];
    #pragma unroll
    for (int i = 0; i < 4; ++i) {
      int mbase = gc.m0 + wm * 64 + i * 16 + lq * 4;
      #pragma unroll
      for (int r = 0; r < 4; ++r) {
        float v = fmaxf(acc[i][j][r] + bv, 0.0f);
        C[(size_t)(mbase + r) * DD + n] = f2bf(v);
      }
    }
  }
}

// plain gemm (layers 1 and 2)
__global__ __launch_bounds__(512, 2) void gemm_relu_kernel(
    const unsigned short* __restrict__ A,
    const unsigned short* __restrict__ W,
    const float* __restrict__ bias,
    unsigned short* __restrict__ C)
{
  __shared__ unsigned short ldsA[3][16384];   // 96 KiB
  __shared__ unsigned short ldsB[3][8192];    // 48 KiB
  const int t = threadIdx.x;
  Coords256 gc = coords256(blockIdx.x, t);
  f32x4 acc[4][4] = {};
  gemm_mainloop8p(A, W, ldsA, ldsB, gc, t, acc);
  epilogue_store256(gc, t, acc, bias, C);
}

// layer 3 + dot with wo, NO atomics / NO d_out access:
// Pbuf[nt*4096 + m] = sum_{n in this block's 128 cols} relu(acc+b2[n])*wo[n]
__global__ __launch_bounds__(512, 2) void gemm_relu_dot_kernel(
    const unsigned short* __restrict__ A,
    const unsigned short* __restrict__ W,
    const float* __restrict__ bias,
    const float* __restrict__ wo,
    float* __restrict__ Pbuf)
{
  __shared__ unsigned short ldsA[3][16384];
  __shared__ unsigned short ldsB[3][8192];
  const int t = threadIdx.x;

  Coords256 gc = coords256(blockIdx.x, t);
  f32x4 acc[4][4] = {};
  gemm_mainloop8p(A, W, ldsA, ldsB, gc, t, acc);

  const int l = t & 63, lq = l >> 4, lr = l & 15;
  const int w = t >> 6, wm = w & 3, wn = w >> 2;

  float bv[4], wv[4];
  #pragma unroll
  for (int j = 0; j < 4; ++j) {
    int n = gc.n0 + wn * 64 + j * 16 + lr;
    bv[j] = bias[n];
    wv[j] = wo[n];
  }
  float partial[4][4];
  #pragma unroll
  for (int i = 0; i < 4; ++i)
    #pragma unroll
    for (int r = 0; r < 4; ++r) {
      float s = 0.0f;
      #pragma unroll
      for (int j = 0; j < 4; ++j)
        s += fmaxf(acc[i][j][r] + bv[j], 0.0f) * wv[j];
      partial[i][r] = s;
    }

  // butterfly over lr (lane bits 0..3)
  #pragma unroll
  for (int d = 1; d <= 8; d <<= 1)
    #pragma unroll
    for (int i = 0; i < 4; ++i)
      #pragma unroll
      for (int r = 0; r < 4; ++r)
        partial[i][r] += __shfl_xor(partial[i][r], d, 64);

  // cross-wave reduce via LDS (mainloop ended with trailing s_barrier:
  // all waves are past every read of ldsA).
  float* sRed = (float*)ldsA;   // [256 rows][2 col-halves]
  if (lr == 0) {
    #pragma unroll
    for (int i = 0; i < 4; ++i)
      #pragma unroll
      for (int r = 0; r < 4; ++r) {
        int row = wm * 64 + i * 16 + lq * 4 + r;   // 0..255 in tile
        sRed[row * 2 + wn] = partial[i][r];
      }
  }
  __syncthreads();
  if (t < 256) {
    float s = sRed[t * 2 + 0] + sRed[t * 2 + 1];
    int nt = gc.n0 >> 7;
    Pbuf[nt * BB + gc.m0 + t] = s;
  }
}

// final reduce: out[m] = bo + sum_{nt<16} Pbuf[nt*4096+m]  (overwrite-only)
__global__ __launch_bounds__(256) void reduce_out_kernel(
    const float* __restrict__ Pbuf,
    const float* __restrict__ bmuo, const float* __restrict__ brhoo,
    const float* __restrict__ epsbo,
    float* __restrict__ out)
{
  const int m = blockIdx.x * 256 + threadIdx.x;
  float s = bmuo[0] + epsbo[0] * sp(brhoo[0]);
  #pragma unroll
  for (int nt = 0; nt < 16; ++nt)
    s += Pbuf[nt * BB + m];
  out[m] = s;
}

// ---------------- launch ----------------
extern "C" void kernel_launch(void* const* d_in, const int* in_sizes, int n_in,
                              void* d_out, int out_size, void* d_ws, size_t ws_size,
                              hipStream_t stream) {
  const float* x     = (const float*)d_in[0];
  const float* wmuh  = (const float*)d_in[1];
  const float* wrhoh = (const float*)d_in[2];
  const float* bmuh  = (const float*)d_in[3];
  const float* brhoh = (const float*)d_in[4];
  const float* wmuo  = (const float*)d_in[5];
  const float* wrhoo = (const float*)d_in[6];
  const float* bmuo  = (const float*)d_in[7];
  const float* brhoo = (const float*)d_in[8];
  const float* epswh = (const float*)d_in[9];
  const float* epsbh = (const float*)d_in[10];
  const float* epswo = (const float*)d_in[11];
  const float* epsbo = (const float*)d_in[12];

  char* ws = (char*)d_ws;
  unsigned short* Wh = (unsigned short*)(ws);                       // 25165824 B
  unsigned short* Xb = (unsigned short*)(ws + 25165824);            // 16777216 B
  unsigned short* Ha = (unsigned short*)(ws + 25165824 + 16777216);
  unsigned short* Hb = (unsigned short*)(ws + 25165824 + 2 * 16777216);
  float* bh   = (float*)(ws + 25165824 + 3 * 16777216);             // 24576 B
  float* wo   = (float*)(ws + 25165824 + 3 * 16777216 + 24576);     // 8192 B
  float* Pbuf = (float*)(ws + 25165824 + 3 * 16777216 + 24576 + 8192); // 262144 B

  prep0_kernel<<<2561, 512, 0, stream>>>(
      x, wmuh, wrhoh, bmuh, brhoh, wmuo, wrhoo,
      epswh, epsbh, epswo, Wh, Xb, bh, wo);

  gemm_relu_kernel<<<NGEMM, 512, 0, stream>>>(Xb, Wh, bh, Ha);

  gemm_relu_kernel<<<NGEMM, 512, 0, stream>>>(Ha, Wh + 1 * 4194304, bh + DD, Hb);

  gemm_relu_dot_kernel<<<NGEMM, 512, 0, stream>>>(
      Hb, Wh + 2 * 4194304, bh + 2 * DD, wo, Pbuf);

  reduce_out_kernel<<<BB / 256, 256, 0, stream>>>(
      Pbuf, bmuo, brhoo, epsbo, (float*)d_out);
}

// Round 7
// 306.544 us; speedup vs baseline: 1.0946x; 1.0946x over previous
//
#include <hip/hip_runtime.h>

// ---------------- problem constants ----------------
// B=4096 batch, D=2048 dim, H=3 hidden layers, O=1 output
#define BB 4096
#define DD 2048

typedef float f32x4 __attribute__((ext_vector_type(4)));
typedef __bf16 bf16x8 __attribute__((ext_vector_type(8)));

typedef __attribute__((address_space(1))) unsigned int gl_u32;
typedef __attribute__((address_space(3))) unsigned int lds_u32;

#define GLOAD_LDS16(gptr, sptr) \
  __builtin_amdgcn_global_load_lds((gl_u32*)(void*)(gptr), (lds_u32*)(sptr), 16, 0, 0)

// raw barrier with compiler memory fence (does NOT force vmcnt(0) drain like
// __syncthreads) — required for counted-vmcnt pipelining (T3/T4).
#define SBAR_MEM() asm volatile("s_barrier" ::: "memory")
#define VMCNT(n)   asm volatile("s_waitcnt vmcnt(" #n ")" ::: "memory")

__device__ __forceinline__ unsigned short f2bf(float f) {
  unsigned int u = __float_as_uint(f);
  u += 0x7fffu + ((u >> 16) & 1u);   // round-to-nearest-even
  return (unsigned short)(u >> 16);
}

// fast softplus: v_exp_f32 + v_log_f32 (quarter-rate HW ops).
__device__ __forceinline__ float sp(float x) {
  float t = __expf(-fabsf(x));
  return fmaxf(x, 0.0f) + __logf(1.0f + t);
}

__device__ __forceinline__ void prep_f32_vec4(
    const float* __restrict__ mu, const float* __restrict__ rho,
    const float* __restrict__ eps, float* __restrict__ out, long long i)
{
  float4 m = ((const float4*)mu)[i];
  float4 r = ((const float4*)rho)[i];
  float4 e = ((const float4*)eps)[i];
  float4 o;
  o.x = m.x + e.x * sp(r.x);
  o.y = m.y + e.y * sp(r.y);
  o.z = m.z + e.z * sp(r.z);
  o.w = m.w + e.w * sp(r.w);
  ((float4*)out)[i] = o;
}

// ---------------- prep0: ALL prep, BATCHED loads (R12) ----------------
// R6 post-mortem: prep0 ran at 3.1 TB/s, VGPR_Count=24 — the per-vec4
// helper serialized to load->wait->compute->store (~3 loads in flight).
// Fix: load ALL 12 float4 into registers first (12 outstanding/wave,
// ~192 in flight/CU at 16 waves), then convert+store. Same arithmetic.
__global__ __launch_bounds__(512) void prep0_kernel(
    const float* __restrict__ x,
    const float* __restrict__ wmuh, const float* __restrict__ wrhoh,
    const float* __restrict__ bmuh, const float* __restrict__ brhoh,
    const float* __restrict__ wmuo, const float* __restrict__ wrhoo,
    const float* __restrict__ epswh, const float* __restrict__ epsbh,
    const float* __restrict__ epswo,
    unsigned short* __restrict__ Wh, unsigned short* __restrict__ Xb,
    float* __restrict__ bh, float* __restrict__ wo)
{
  const int b = blockIdx.x;
  const int t = threadIdx.x;
  if (b < 1536) {          // all 3 W layers: 3*2048*2048/4 = 3145728 vec4
    long long base = (long long)b * 2048 + t;
    float4 m[4], r[4], e[4];
    #pragma unroll
    for (int j = 0; j < 4; ++j) m[j] = ((const float4*)wmuh)[base + j * 512];
    #pragma unroll
    for (int j = 0; j < 4; ++j) r[j] = ((const float4*)wrhoh)[base + j * 512];
    #pragma unroll
    for (int j = 0; j < 4; ++j) e[j] = ((const float4*)epswh)[base + j * 512];
    #pragma unroll
    for (int j = 0; j < 4; ++j) {
      ushort4 o;
      o.x = f2bf(m[j].x + e[j].x * sp(r[j].x));
      o.y = f2bf(m[j].y + e[j].y * sp(r[j].y));
      o.z = f2bf(m[j].z + e[j].z * sp(r[j].z));
      o.w = f2bf(m[j].w + e[j].w * sp(r[j].w));
      ((ushort4*)Wh)[base + j * 512] = o;
    }
    return;
  }
  if (b < 2560) {          // x -> bf16: 4096*2048/4 = 2097152 vec4
    long long base = (long long)(b - 1536) * 2048 + t;
    float4 v[4];
    #pragma unroll
    for (int j = 0; j < 4; ++j) v[j] = ((const float4*)x)[base + j * 512];
    #pragma unroll
    for (int j = 0; j < 4; ++j) {
      ushort4 o;
      o.x = f2bf(v[j].x); o.y = f2bf(v[j].y);
      o.z = f2bf(v[j].z); o.w = f2bf(v[j].w);
      ((ushort4*)Xb)[base + j * 512] = o;
    }
    return;
  }
  // b == 2560: b0,b1,b2 (1536 vec4) + wo (512 vec4)
  #pragma unroll
  for (int j = 0; j < 3; ++j)
    prep_f32_vec4(bmuh, brhoh, epsbh, bh, j * 512 + t);
  prep_f32_vec4(wmuo, wrhoo, epswo, wo, t);
}

// ---------------- R12 GEMM core: 256x128, ring-3, FINE interleave --------
// R6 post-mortem: ds_reads issued AFTER the certify barrier + full
// lgkmcnt(0) before each MFMA cluster -> all 8 waves (1 block/CU) sat in
// the same exposed ds_read latency window every phase (m196 anti-pattern).
// Fix (m201 mechanism): per K-tile, ONE certify barrier (counted vmcnt(6),
// never 0 until tail), then issue ALL 16 ds_reads (both k-halves)
// interleaved with stage(k+2) issue, then MFMA half0 (compiler emits
// lgkmcnt(8)) and MFMA half1 (lgkmcnt(0)) under setprio, then ONE trailing
// barrier. ds_read latency hides under the barrier + the other half's
// MFMA; mid-phase barrier deleted (read-read on certified buffer).
// vmcnt ledger: 6 loads/tile; prologue 12 outstanding; certify k<=30 ->
// vmcnt(6) retires exactly stage(k); k==31 -> vmcnt(0).
// Ring-3 reuse: stage(k+2) targets the buffer last read at tile k-1, whose
// trailing barrier precedes this issue (verified passing in R5/R6).
#define NGEMM 256

struct Coords256 { int m0, n0; int srow[4], sgc[4]; };

__device__ __forceinline__ Coords256 coords256(int id, int t) {
  Coords256 g;
  const int p = id & 7;        // XCD patch (L2 locality)
  const int i4 = id >> 3;      // 0..31 within patch
  const int mt = (p & 3) * 4 + (i4 & 3);     // 0..15
  const int nt = (p >> 2) * 8 + (i4 >> 2);   // 0..15
  g.m0 = mt * 256;
  g.n0 = nt * 128;
  #pragma unroll
  for (int i = 0; i < 4; ++i) {
    int c = i * 512 + t;
    g.srow[i] = c >> 3;                      // 0..255
    g.sgc[i] = (c & 7) ^ (g.srow[i] & 7);    // XOR swizzle folded into gsrc
  }
  return g;
}

// half 0: A rows 0..127 (2 loads) + B rows 0..63 (1 load)
__device__ __forceinline__ void stage_half0(
    const unsigned short* __restrict__ A, const unsigned short* __restrict__ W,
    unsigned short* bufA, unsigned short* bufB,
    const Coords256& gc, int kt, int t)
{
  #pragma unroll
  for (int i = 0; i < 2; ++i) {
    int c = i * 512 + t;
    const unsigned short* ga = A + (size_t)(gc.m0 + gc.srow[i]) * DD + kt + gc.sgc[i] * 8;
    GLOAD_LDS16(ga, &bufA[c * 8]);
  }
  const unsigned short* gb = W + (size_t)(gc.n0 + gc.srow[0]) * DD + kt + gc.sgc[0] * 8;
  GLOAD_LDS16(gb, &bufB[t * 8]);
}

// half 1: A rows 128..255 (2 loads) + B rows 64..127 (1 load)
__device__ __forceinline__ void stage_half1(
    const unsigned short* __restrict__ A, const unsigned short* __restrict__ W,
    unsigned short* bufA, unsigned short* bufB,
    const Coords256& gc, int kt, int t)
{
  #pragma unroll
  for (int i = 2; i < 4; ++i) {
    int c = i * 512 + t;
    const unsigned short* ga = A + (size_t)(gc.m0 + gc.srow[i]) * DD + kt + gc.sgc[i] * 8;
    GLOAD_LDS16(ga, &bufA[c * 8]);
  }
  const unsigned short* gb = W + (size_t)(gc.n0 + gc.srow[1]) * DD + kt + gc.sgc[1] * 8;
  GLOAD_LDS16(gb, &bufB[(512 + t) * 8]);
}

// issue 8 ds_read_b128 for k-half s (compiler tracks deps, emits counted
// lgkmcnt before the consuming MFMAs — m97-verified behavior).
__device__ __forceinline__ void read_frags(
    const unsigned short* bufA, const unsigned short* bufB, int s,
    int wm, int wn, int lq, int lr, bf16x8 (&af)[4], bf16x8 (&bv)[4])
{
  const int g = s * 4 + lq;
  const int go = (g ^ (lr & 7)) * 8;   // row&7 == lr&7 (wm*64, i*16 mult of 8)
  #pragma unroll
  for (int i = 0; i < 4; ++i)
    af[i] = *(const bf16x8*)&bufA[(wm * 64 + i * 16 + lr) * 64 + go];
  #pragma unroll
  for (int j = 0; j < 4; ++j)
    bv[j] = *(const bf16x8*)&bufB[(wn * 64 + j * 16 + lr) * 64 + go];
}

__device__ __forceinline__ void mfma_half(
    bf16x8 (&af)[4], bf16x8 (&bv)[4], f32x4 (&acc)[4][4])
{
  __builtin_amdgcn_s_setprio(1);
  #pragma unroll
  for (int i = 0; i < 4; ++i)
    #pragma unroll
    for (int j = 0; j < 4; ++j)
      acc[i][j] = __builtin_amdgcn_mfma_f32_16x16x32_bf16(af[i], bv[j], acc[i][j], 0, 0, 0);
  __builtin_amdgcn_s_setprio(0);
}

__device__ __forceinline__ void gemm_mainloop_fine(
    const unsigned short* __restrict__ A, const unsigned short* __restrict__ W,
    unsigned short (*ldsA)[16384], unsigned short (*ldsB)[8192],
    const Coords256& gc, int t, f32x4 (&acc)[4][4])
{
  const int l = t & 63, lq = l >> 4, lr = l & 15;
  const int w = t >> 6, wm = w & 3, wn = w >> 2;
  unsigned short *a0 = ldsA[0], *a1 = ldsA[1], *a2 = ldsA[2];
  unsigned short *b0 = ldsB[0], *b1 = ldsB[1], *b2 = ldsB[2];
  // prologue: tiles 0,1 fully staged (12 loads outstanding)
  stage_half0(A, W, a0, b0, gc, 0, t);
  stage_half1(A, W, a0, b0, gc, 0, t);
  stage_half0(A, W, a1, b1, gc, 64, t);
  stage_half1(A, W, a1, b1, gc, 64, t);
  for (int k = 0; k < 32; ++k) {
    if (k < 31) { VMCNT(6); }        // retire exactly stage(k); 6 in flight
    else        { VMCNT(0); }
    SBAR_MEM();                      // tile k certified for all waves
    bf16x8 a0f[4], b0f[4], a1f[4], b1f[4];
    read_frags(a0, b0, 0, wm, wn, lq, lr, a0f, b0f);
    if (k < 30) stage_half0(A, W, a2, b2, gc, (k + 2) * 64, t);
    read_frags(a0, b0, 1, wm, wn, lq, lr, a1f, b1f);
    if (k < 30) stage_half1(A, W, a2, b2, gc, (k + 2) * 64, t);
    mfma_half(a0f, b0f, acc);        // compiler waits lgkmcnt(8)
    mfma_half(a1f, b1f, acc);        // compiler waits lgkmcnt(0)
    SBAR_MEM();                      // all waves done reading tile k
    unsigned short* ta = a0; a0 = a1; a1 = a2; a2 = ta;
    unsigned short* tb = b0; b0 = b1; b1 = b2; b2 = tb;
  }
}

__device__ __forceinline__ void epilogue_store256(
    const Coords256& gc, int t, f32x4 (&acc)[4][4],
    const float* __restrict__ bias, unsigned short* __restrict__ C)
{
  const int l = t & 63, lq = l >> 4, lr = l & 15;
  const int w = t >> 6, wm = w & 3, wn = w >> 2;
  #pragma unroll
  for (int j = 0; j < 4; ++j) {
    int n = gc.n0 + wn * 64 + j * 16 + lr;
    float bv = bias[n];
    #pragma unroll
    for (int i = 0; i < 4; ++i) {
      int mbase = gc.m0 + wm * 64 + i * 16 + lq * 4;
      #pragma unroll
      for (int r = 0; r < 4; ++r) {
        float v = fmaxf(acc[i][j][r] + bv, 0.0f);
        C[(size_t)(mbase + r) * DD + n] = f2bf(v);
      }
    }
  }
}

// plain gemm (layers 1 and 2)
__global__ __launch_bounds__(512, 2) void gemm_relu_kernel(
    const unsigned short* __restrict__ A,
    const unsigned short* __restrict__ W,
    const float* __restrict__ bias,
    unsigned short* __restrict__ C)
{
  __shared__ unsigned short ldsA[3][16384];   // 96 KiB
  __shared__ unsigned short ldsB[3][8192];    // 48 KiB
  const int t = threadIdx.x;
  Coords256 gc = coords256(blockIdx.x, t);
  f32x4 acc[4][4] = {};
  gemm_mainloop_fine(A, W, ldsA, ldsB, gc, t, acc);
  epilogue_store256(gc, t, acc, bias, C);
}

// layer 3 + dot with wo, NO atomics / NO d_out access:
// Pbuf[nt*4096 + m] = sum_{n in this block's 128 cols} relu(acc+b2[n])*wo[n]
__global__ __launch_bounds__(512, 2) void gemm_relu_dot_kernel(
    const unsigned short* __restrict__ A,
    const unsigned short* __restrict__ W,
    const float* __restrict__ bias,
    const float* __restrict__ wo,
    float* __restrict__ Pbuf)
{
  __shared__ unsigned short ldsA[3][16384];
  __shared__ unsigned short ldsB[3][8192];
  const int t = threadIdx.x;

  Coords256 gc = coords256(blockIdx.x, t);
  f32x4 acc[4][4] = {};
  gemm_mainloop_fine(A, W, ldsA, ldsB, gc, t, acc);

  const int l = t & 63, lq = l >> 4, lr = l & 15;
  const int w = t >> 6, wm = w & 3, wn = w >> 2;

  float bv[4], wv[4];
  #pragma unroll
  for (int j = 0; j < 4; ++j) {
    int n = gc.n0 + wn * 64 + j * 16 + lr;
    bv[j] = bias[n];
    wv[j] = wo[n];
  }
  float partial[4][4];
  #pragma unroll
  for (int i = 0; i < 4; ++i)
    #pragma unroll
    for (int r = 0; r < 4; ++r) {
      float s = 0.0f;
      #pragma unroll
      for (int j = 0; j < 4; ++j)
        s += fmaxf(acc[i][j][r] + bv[j], 0.0f) * wv[j];
      partial[i][r] = s;
    }

  // butterfly over lr (lane bits 0..3)
  #pragma unroll
  for (int d = 1; d <= 8; d <<= 1)
    #pragma unroll
    for (int i = 0; i < 4; ++i)
      #pragma unroll
      for (int r = 0; r < 4; ++r)
        partial[i][r] += __shfl_xor(partial[i][r], d, 64);

  // cross-wave reduce via LDS (mainloop ended with trailing s_barrier:
  // all waves are past every read of ldsA).
  float* sRed = (float*)ldsA;   // [256 rows][2 col-halves]
  if (lr == 0) {
    #pragma unroll
    for (int i = 0; i < 4; ++i)
      #pragma unroll
      for (int r = 0; r < 4; ++r) {
        int row = wm * 64 + i * 16 + lq * 4 + r;   // 0..255 in tile
        sRed[row * 2 + wn] = partial[i][r];
      }
  }
  __syncthreads();
  if (t < 256) {
    float s = sRed[t * 2 + 0] + sRed[t * 2 + 1];
    int nt = gc.n0 >> 7;
    Pbuf[nt * BB + gc.m0 + t] = s;
  }
}

// final reduce: out[m] = bo + sum_{nt<16} Pbuf[nt*4096+m]  (overwrite-only)
__global__ __launch_bounds__(256) void reduce_out_kernel(
    const float* __restrict__ Pbuf,
    const float* __restrict__ bmuo, const float* __restrict__ brhoo,
    const float* __restrict__ epsbo,
    float* __restrict__ out)
{
  const int m = blockIdx.x * 256 + threadIdx.x;
  float s = bmuo[0] + epsbo[0] * sp(brhoo[0]);
  #pragma unroll
  for (int nt = 0; nt < 16; ++nt)
    s += Pbuf[nt * BB + m];
  out[m] = s;
}

// ---------------- launch ----------------
extern "C" void kernel_launch(void* const* d_in, const int* in_sizes, int n_in,
                              void* d_out, int out_size, void* d_ws, size_t ws_size,
                              hipStream_t stream) {
  const float* x     = (const float*)d_in[0];
  const float* wmuh  = (const float*)d_in[1];
  const float* wrhoh = (const float*)d_in[2];
  const float* bmuh  = (const float*)d_in[3];
  const float* brhoh = (const float*)d_in[4];
  const float* wmuo  = (const float*)d_in[5];
  const float* wrhoo = (const float*)d_in[6];
  const float* bmuo  = (const float*)d_in[7];
  const float* brhoo = (const float*)d_in[8];
  const float* epswh = (const float*)d_in[9];
  const float* epsbh = (const float*)d_in[10];
  const float* epswo = (const float*)d_in[11];
  const float* epsbo = (const float*)d_in[12];

  char* ws = (char*)d_ws;
  unsigned short* Wh = (unsigned short*)(ws);                       // 25165824 B
  unsigned short* Xb = (unsigned short*)(ws + 25165824);            // 16777216 B
  unsigned short* Ha = (unsigned short*)(ws + 25165824 + 16777216);
  unsigned short* Hb = (unsigned short*)(ws + 25165824 + 2 * 16777216);
  float* bh   = (float*)(ws + 25165824 + 3 * 16777216);             // 24576 B
  float* wo   = (float*)(ws + 25165824 + 3 * 16777216 + 24576);     // 8192 B
  float* Pbuf = (float*)(ws + 25165824 + 3 * 16777216 + 24576 + 8192); // 262144 B

  prep0_kernel<<<2561, 512, 0, stream>>>(
      x, wmuh, wrhoh, bmuh, brhoh, wmuo, wrhoo,
      epswh, epsbh, epswo, Wh, Xb, bh, wo);

  gemm_relu_kernel<<<NGEMM, 512, 0, stream>>>(Xb, Wh, bh, Ha);

  gemm_relu_kernel<<<NGEMM, 512, 0, stream>>>(Ha, Wh + 1 * 4194304, bh + DD, Hb);

  gemm_relu_dot_kernel<<<NGEMM, 512, 0, stream>>>(
      Hb, Wh + 2 * 4194304, bh + 2 * DD, wo, Pbuf);

  reduce_out_kernel<<<BB / 256, 256, 0, stream>>>(
      Pbuf, bmuo, brhoo, epsbo, (float*)d_out);
}